// Round 4
// baseline (348.493 us; speedup 1.0000x reference)
//
#include <hip/hip_runtime.h>
#include <cstdint>
#include <cstddef>

#define T_TOK 64
#define K_IN 4096
#define N_OUT 14336
#define SPLITK 16
#define KCHUNK 256                   // K per block (4096/16)
#define BK 32                        // k-rows per B stage
#define NSTAGES (KCHUNK / BK)        // 8
#define NCOLS 64                     // cols per block (16 per wave)
#define DEPTH 2                      // B ring slots per wave (was 4)
#define A_BYTES 32768                // 64 rows x 512 B, XOR-swizzled (no pad)
#define B_WAVE_BYTES (DEPTH * BK * 16 * 4)   // 4096 per wave
#define LDS_TOTAL (A_BYTES + 4 * B_WAVE_BYTES)  // 49152 -> 3 blocks/CU

typedef __attribute__((ext_vector_type(8))) short bf16x8;
typedef __attribute__((ext_vector_type(4))) float f32x4;

static __device__ __forceinline__ unsigned short bf16_rne(float f) {
    unsigned u = __builtin_bit_cast(unsigned, f);
    unsigned r = (u + 0x7fffu + ((u >> 16) & 1u)) >> 16;
    return (unsigned short)r;
}

// Kernel 1: out = bias + rowsum(x_t) * u. Grid (N_OUT/4/256 = 14, T_TOK).
// Each block computes its token's rowsum inline (x row = 16 KB, L2-resident).
__global__ __launch_bounds__(256) void init_kernel(const float* __restrict__ x,
                                                   const float* __restrict__ u,
                                                   const float* __restrict__ bias,
                                                   float* __restrict__ out) {
    const int t = blockIdx.y;
    const int tid = threadIdx.x;
    const float4* x4 = (const float4*)(x + (size_t)t * K_IN);
    float s = 0.f;
#pragma unroll
    for (int i = 0; i < 4; i++) {
        float4 v = x4[i * 256 + tid];
        s += v.x + v.y + v.z + v.w;
    }
#pragma unroll
    for (int off = 32; off > 0; off >>= 1) s += __shfl_down(s, off, 64);
    __shared__ float part[4];
    if ((tid & 63) == 0) part[tid >> 6] = s;
    __syncthreads();
    const float rs = part[0] + part[1] + part[2] + part[3];

    const int n4 = blockIdx.x * 256 + tid;
    float4 b = ((const float4*)bias)[n4];
    float4 uu = ((const float4*)u)[n4];
    float4 o;
    o.x = b.x + rs * uu.x; o.y = b.y + rs * uu.y;
    o.z = b.z + rs * uu.z; o.w = b.w + rs * uu.w;
    ((float4*)(out + (size_t)t * N_OUT))[n4] = o;
}

// Kernel 2: split-K int4-dequant GEMM, BARRIER-FREE K-loop.
// Grid (224, 16) x 256 thr. Block = 64 cols x 256 k; wave owns a private
// 16-col strip. B is DMA'd (global_load_lds) into a per-wave depth-2 LDS ring
// (2 KB/stage); the wave syncs on its own queue with counted s_waitcnt
// vmcnt(N) (never 0 in the steady loop, no __syncthreads in the loop).
// LDS = 48 KB -> 3 blocks/CU (12 waves/CU, same 48 KB/CU DMA in flight as
// the depth-4/2-block config, but better staging-bubble/epilogue overlap).
__global__ __launch_bounds__(256, 3) void gemm_kernel(const float* __restrict__ x,
                                                      const int* __restrict__ W,
                                                      const float* __restrict__ scales,
                                                      float* __restrict__ out) {
    __shared__ char lds[LDS_TOTAL];
    char* Alds = lds;

    const int tid = threadIdx.x;
    const int wave = tid >> 6;
    const int lane = tid & 63;
    const int q = lane >> 4;            // quad: k-offset q*8 in frags
    const int r = lane & 15;            // col within wave strip / token row
    const int cb = blockIdx.x;
    const int kbase = blockIdx.y * KCHUNK;
    const int col = cb * NCOLS + wave * 16 + r;

    // two 128-group scales covering this block's 256-k chunk
    const int g0 = kbase >> 7;
    const float sc0 = scales[(size_t)g0 * N_OUT + col];
    const float sc1 = scales[(size_t)(g0 + 1) * N_OUT + col];

    // ---- stage A once from x fp32: 64 rows x 256 k -> bf16, chunk cc (16 B
    // of bf16 = 8 k) stored at cc^(row&7). Two passes of 4 chunks to keep
    // the live float4 set at 32 VGPR (fits __launch_bounds__(256,3)).
#pragma unroll
    for (int half = 0; half < 2; half++) {
        float4 av[4][2];
#pragma unroll
        for (int i = 0; i < 4; i++) {
            const int chunk = (half * 4 + i) * 256 + tid;   // 2048 chunks of 8 k
            const int row = chunk >> 5;
            const int cc = chunk & 31;
            const float* src = x + (size_t)row * K_IN + kbase + cc * 8;
            av[i][0] = *(const float4*)(src);
            av[i][1] = *(const float4*)(src + 4);
        }
#pragma unroll
        for (int i = 0; i < 4; i++) {
            const int chunk = (half * 4 + i) * 256 + tid;
            const int row = chunk >> 5;
            const int cc = chunk & 31;
            const float4 a0 = av[i][0], a1 = av[i][1];
            ushort4 h0, h1;
            h0.x = bf16_rne(a0.x); h0.y = bf16_rne(a0.y);
            h0.z = bf16_rne(a0.z); h0.w = bf16_rne(a0.w);
            h1.x = bf16_rne(a1.x); h1.y = bf16_rne(a1.y);
            h1.z = bf16_rne(a1.z); h1.w = bf16_rne(a1.w);
            char* dst = Alds + row * 512 + (cc ^ (row & 7)) * 16;
            *(ushort4*)dst = h0;
            *(ushort4*)(dst + 8) = h1;
        }
    }
    __syncthreads();   // ONLY barrier: A visible to all waves (before DMA issues)

    char* Bring = lds + A_BYTES + wave * B_WAVE_BYTES;

    // per-wave B DMA: stage = 16 cols x 32 k = 2 KB = 2 instrs x 1 KB.
    // lane -> (k_local = lane>>2, colq = lane&3); LDS dest = base + lane*16
    // gives [k][col16] rows of 64 B. Global side matches: 64 B per k-row.
    auto issue_stage = [&](int s) {
        char* slot = Bring + (s & (DEPTH - 1)) * (BK * 64);
#pragma unroll
        for (int j = 0; j < 2; j++) {
            const int krow = kbase + s * BK + j * 16 + (lane >> 2);
            const int* g = W + (size_t)krow * N_OUT + cb * NCOLS + wave * 16 + (lane & 3) * 4;
            void* l = (void*)(slot + j * 1024);
            __builtin_amdgcn_global_load_lds(
                (const __attribute__((address_space(1))) void*)g,
                (__attribute__((address_space(3))) void*)l, 16, 0, 0);
        }
    };

    f32x4 acc[4];
#pragma unroll
    for (int mt = 0; mt < 4; mt++) acc[mt] = f32x4{0.f, 0.f, 0.f, 0.f};

    auto compute_stage = [&](int s) {
        const char* slot = Bring + (s & (DEPTH - 1)) * (BK * 64);
        const float scs = (s < 4) ? sc0 : sc1;        // group = (kbase+s*32)/128
        int bi[8];
#pragma unroll
        for (int jj = 0; jj < 8; jj++)
            bi[jj] = *(const int*)(slot + (q * 8 + jj) * 64 + r * 4);
        bf16x8 bf;
#pragma unroll
        for (int jj = 0; jj < 8; jj++) bf[jj] = (short)bf16_rne((float)bi[jj] * scs);
#pragma unroll
        for (int mt = 0; mt < 4; mt++) {
            const int row = r + mt * 16;
            bf16x8 af = *(const bf16x8*)(Alds + row * 512 + (((s * 4 + q) ^ (r & 7)) * 16));
            acc[mt] = __builtin_amdgcn_mfma_f32_16x16x32_bf16(af, bf, acc[mt], 0, 0, 0);
        }
    };

    // prologue: fill the depth-2 ring (4 DMA instrs in flight)
    issue_stage(0); issue_stage(1);

    // vmcnt(N) waits until only N vm-ops outstanding; stage s needs its own 2
    // instrs done (the following stage's 2 may remain in flight). simm16:
    // lgkmcnt=15 (0xF00) | expcnt=7 (0x70) | vmcnt low bits.
#define GEMM_STAGE(S, WN)                                   \
    {                                                       \
        __builtin_amdgcn_s_waitcnt(0x0F70 | (WN));          \
        compute_stage(S);                                   \
        if ((S) + DEPTH < NSTAGES) issue_stage((S) + DEPTH);\
    }
    GEMM_STAGE(0, 2) GEMM_STAGE(1, 2) GEMM_STAGE(2, 2) GEMM_STAGE(3, 2)
    GEMM_STAGE(4, 2) GEMM_STAGE(5, 2) GEMM_STAGE(6, 2) GEMM_STAGE(7, 0)
#undef GEMM_STAGE

    // epilogue: atomic accumulate partials (C/D layout: row = q*4+i, col = col)
#pragma unroll
    for (int mt = 0; mt < 4; mt++) {
#pragma unroll
        for (int i = 0; i < 4; i++) {
            const int t = mt * 16 + q * 4 + i;
            atomicAdd(out + (size_t)t * N_OUT + col, acc[mt][i]);
        }
    }
}

extern "C" void kernel_launch(void* const* d_in, const int* in_sizes, int n_in,
                              void* d_out, int out_size, void* d_ws, size_t ws_size,
                              hipStream_t stream) {
    const float* x      = (const float*)d_in[0];
    const int*   W      = (const int*)d_in[1];
    const float* scales = (const float*)d_in[2];
    const float* u      = (const float*)d_in[3];
    const float* bias   = (const float*)d_in[4];
    float* out = (float*)d_out;

    init_kernel<<<dim3(N_OUT / 4 / 256, T_TOK), 256, 0, stream>>>(x, u, bias, out);
    gemm_kernel<<<dim3(N_OUT / NCOLS, SPLITK), 256, 0, stream>>>(x, W, scales, out);
}

// Round 5
// 341.278 us; speedup vs baseline: 1.0211x; 1.0211x over previous
//
#include <hip/hip_runtime.h>
#include <cstdint>
#include <cstddef>

#define T_TOK 64
#define K_IN 4096
#define N_OUT 14336
#define SPLITK 16
#define KCHUNK 256                   // K per block (4096/16)
#define BK 32                        // k-rows per B stage
#define NSTAGES (KCHUNK / BK)        // 8
#define NCOLS 64                     // cols per block (16 per wave)
#define DEPTH 4                      // B ring slots per wave
#define A_BYTES 32768                // 64 rows x 512 B, XOR-swizzled (no pad)
#define B_WAVE_BYTES (DEPTH * BK * 16 * 4)   // 8192 per wave
#define LDS_TOTAL (A_BYTES + 4 * B_WAVE_BYTES)  // 65536

typedef __attribute__((ext_vector_type(8))) short bf16x8;
typedef __attribute__((ext_vector_type(4))) float f32x4;

static __device__ __forceinline__ unsigned short bf16_rne(float f) {
    unsigned u = __builtin_bit_cast(unsigned, f);
    unsigned r = (u + 0x7fffu + ((u >> 16) & 1u)) >> 16;
    return (unsigned short)r;
}

// Kernel 1: fused prep+init. One block per token: x row -> bf16 copy in ws,
// rowsum in-block, then out[t,:] = bias + rowsum*u (init folded in, saving a
// launch + init's redundant per-block rowsum recomputation).
__global__ __launch_bounds__(256) void prep_init_kernel(const float* __restrict__ x,
                                                        const float* __restrict__ u,
                                                        const float* __restrict__ bias,
                                                        unsigned short* __restrict__ xbf,
                                                        float* __restrict__ out) {
    const int row = blockIdx.x;
    const int t = threadIdx.x;
    const float4* x4 = (const float4*)(x + (size_t)row * K_IN);
    float s = 0.f;
#pragma unroll
    for (int i = 0; i < 4; i++) {
        float4 v = x4[i * 256 + t];
        s += v.x + v.y + v.z + v.w;
        ushort4 h;
        h.x = bf16_rne(v.x); h.y = bf16_rne(v.y);
        h.z = bf16_rne(v.z); h.w = bf16_rne(v.w);
        *(ushort4*)(xbf + (size_t)row * K_IN + (size_t)(i * 256 + t) * 4) = h;
    }
#pragma unroll
    for (int off = 32; off > 0; off >>= 1) s += __shfl_down(s, off, 64);
    __shared__ float part[4];
    if ((t & 63) == 0) part[t >> 6] = s;
    __syncthreads();
    const float rs = part[0] + part[1] + part[2] + part[3];

    float4* o4 = (float4*)(out + (size_t)row * N_OUT);
    const float4* b4 = (const float4*)bias;
    const float4* u4 = (const float4*)u;
#pragma unroll
    for (int i = 0; i < 14; i++) {                 // 14*256 = 3584 = N_OUT/4
        const int n4 = i * 256 + t;
        float4 b = b4[n4];
        float4 uu = u4[n4];
        float4 o;
        o.x = b.x + rs * uu.x; o.y = b.y + rs * uu.y;
        o.z = b.z + rs * uu.z; o.w = b.w + rs * uu.w;
        o4[n4] = o;
    }
}

// Kernel 2: split-K int4-dequant GEMM, BARRIER-FREE K-loop (R0 structure).
// Grid (224, 16) x 256 thr. Block = 64 cols x 256 k; wave owns a private
// 16-col strip. B is DMA'd (global_load_lds) into a per-wave depth-4 LDS ring
// (2 KB/stage); the wave syncs on its own queue with counted s_waitcnt
// vmcnt(N) (never 0 in the steady loop, no __syncthreads in the loop).
// A (64 tok x 256 k bf16, 32 KB) staged once, XOR-swizzled. NEW vs R0: the
// B-ring prologue (8 DMAs) issues BEFORE the A barrier, and the barrier is a
// raw s_barrier + lgkmcnt(0)-only wait (a __syncthreads here would emit
// vmcnt(0) and drain the just-issued DMAs) -> first-stage HBM latency hides
// under the A-store drain instead of being exposed at loop entry.
__global__ __launch_bounds__(256) void gemm_kernel(const unsigned short* __restrict__ xbf,
                                                   const int* __restrict__ W,
                                                   const float* __restrict__ scales,
                                                   float* __restrict__ out) {
    __shared__ char lds[LDS_TOTAL];
    char* Alds = lds;

    const int tid = threadIdx.x;
    const int wave = tid >> 6;
    const int lane = tid & 63;
    const int q = lane >> 4;            // quad: k-offset q*8 in frags
    const int r = lane & 15;            // col within wave strip / token row
    const int cb = blockIdx.x;
    const int kbase = blockIdx.y * KCHUNK;
    const int col = cb * NCOLS + wave * 16 + r;

    // two 128-group scales covering this block's 256-k chunk (issued before
    // the 8 prologue DMAs -> retired by the time vmcnt<=6 holds)
    const int g0 = kbase >> 7;
    const float sc0 = scales[(size_t)g0 * N_OUT + col];
    const float sc1 = scales[(size_t)(g0 + 1) * N_OUT + col];

    char* Bring = lds + A_BYTES + wave * B_WAVE_BYTES;

    // per-wave B DMA: stage = 16 cols x 32 k = 2 KB = 2 instrs x 1 KB.
    // lane -> (k_local = lane>>2, colq = lane&3); LDS dest = base + lane*16
    // gives [k][col16] rows of 64 B. Global side matches: 64 B per k-row.
    auto issue_stage = [&](int s) {
        char* slot = Bring + (s & 3) * (BK * 64);
#pragma unroll
        for (int j = 0; j < 2; j++) {
            const int krow = kbase + s * BK + j * 16 + (lane >> 2);
            const int* g = W + (size_t)krow * N_OUT + cb * NCOLS + wave * 16 + (lane & 3) * 4;
            void* l = (void*)(slot + j * 1024);
            __builtin_amdgcn_global_load_lds(
                (const __attribute__((address_space(1))) void*)g,
                (__attribute__((address_space(3))) void*)l, 16, 0, 0);
        }
    };

    // ---- stage A once: 64 rows x 512 B, chunk cc (16 B) stored at cc^(row&7)
    {
        int4 av[8];
#pragma unroll
        for (int i = 0; i < 8; i++) {
            const int chunk = i * 256 + tid;           // 2048 chunks of 16 B
            const int row = chunk >> 5;
            const int cc = chunk & 31;
            av[i] = *(const int4*)(xbf + (size_t)row * K_IN + kbase + cc * 8);
        }
#pragma unroll
        for (int i = 0; i < 8; i++) {
            const int chunk = i * 256 + tid;
            const int row = chunk >> 5;
            const int cc = chunk & 31;
            *(int4*)(Alds + row * 512 + (cc ^ (row & 7)) * 16) = av[i];
        }
    }

    // prologue DMAs issued BEFORE the barrier (B region disjoint from A)
    issue_stage(0); issue_stage(1); issue_stage(2); issue_stage(3);

    // A visibility: ds_writes drained (lgkmcnt 0) + barrier. vmcnt left at 63
    // so the 8 in-flight DMAs survive the barrier.
    __builtin_amdgcn_sched_barrier(0);
    __builtin_amdgcn_s_waitcnt(0xC07F);       // lgkmcnt(0), vmcnt(63), expcnt(7)
    __builtin_amdgcn_s_barrier();
    __builtin_amdgcn_sched_barrier(0);

    f32x4 acc[4];
#pragma unroll
    for (int mt = 0; mt < 4; mt++) acc[mt] = f32x4{0.f, 0.f, 0.f, 0.f};

    auto compute_stage = [&](int s) {
        const char* slot = Bring + (s & 3) * (BK * 64);
        const float scs = (s < 4) ? sc0 : sc1;        // group = (kbase+s*32)/128
        int bi[8];
#pragma unroll
        for (int jj = 0; jj < 8; jj++)
            bi[jj] = *(const int*)(slot + (q * 8 + jj) * 64 + r * 4);
        bf16x8 bf;
#pragma unroll
        for (int jj = 0; jj < 8; jj++) bf[jj] = (short)bf16_rne((float)bi[jj] * scs);
#pragma unroll
        for (int mt = 0; mt < 4; mt++) {
            const int row = r + mt * 16;
            bf16x8 af = *(const bf16x8*)(Alds + row * 512 + (((s * 4 + q) ^ (r & 7)) * 16));
            acc[mt] = __builtin_amdgcn_mfma_f32_16x16x32_bf16(af, bf, acc[mt], 0, 0, 0);
        }
    };

    // vmcnt(N) waits until only N vm-ops outstanding; stage s needs its own 2
    // instrs done. simm16: lgkmcnt=15 (0xF00) | expcnt=7 (0x70) | vmcnt low bits.
#define GEMM_STAGE(S, WN)                                   \
    {                                                       \
        __builtin_amdgcn_s_waitcnt(0x0F70 | (WN));          \
        compute_stage(S);                                   \
        if ((S) + DEPTH < NSTAGES) issue_stage((S) + DEPTH);\
    }
    GEMM_STAGE(0, 6) GEMM_STAGE(1, 6) GEMM_STAGE(2, 6) GEMM_STAGE(3, 6)
    GEMM_STAGE(4, 6) GEMM_STAGE(5, 4) GEMM_STAGE(6, 2) GEMM_STAGE(7, 0)
#undef GEMM_STAGE

    // epilogue: atomic accumulate partials (C/D layout: row = q*4+i, col = col)
#pragma unroll
    for (int mt = 0; mt < 4; mt++) {
#pragma unroll
        for (int i = 0; i < 4; i++) {
            const int t = mt * 16 + q * 4 + i;
            atomicAdd(out + (size_t)t * N_OUT + col, acc[mt][i]);
        }
    }
}

extern "C" void kernel_launch(void* const* d_in, const int* in_sizes, int n_in,
                              void* d_out, int out_size, void* d_ws, size_t ws_size,
                              hipStream_t stream) {
    const float* x      = (const float*)d_in[0];
    const int*   W      = (const int*)d_in[1];
    const float* scales = (const float*)d_in[2];
    const float* u      = (const float*)d_in[3];
    const float* bias   = (const float*)d_in[4];
    float* out = (float*)d_out;

    unsigned short* xbf = (unsigned short*)d_ws;        // 64*4096*2 = 512 KB

    prep_init_kernel<<<T_TOK, 256, 0, stream>>>(x, u, bias, xbf, out);
    gemm_kernel<<<dim3(N_OUT / NCOLS, SPLITK), 256, 0, stream>>>(xbf, W, scales, out);
}